// Round 1
// baseline (2795.687 us; speedup 1.0000x reference)
//
#include <hip/hip_runtime.h>
#include <math.h>

// Problem constants
constexpr int Bc = 4;
constexpr int Lc = 2048;
constexpr int Dc = 512;
constexpr int Hc = 8;
constexpr int DHc = 64;          // head dim
constexpr int NTOK = Bc * Lc;    // 8192 rows
constexpr float LN_EPS = 1e-5f;

// ---------------------------------------------------------------------------
// Kernel 1: LayerNorm. One wave (64 lanes) per row of 512 floats (8/lane).
// ---------------------------------------------------------------------------
__global__ __launch_bounds__(256) void ln_kernel(const float* __restrict__ x,
                                                 const float* __restrict__ gamma,
                                                 const float* __restrict__ beta,
                                                 float* __restrict__ xn) {
  int wave = threadIdx.x >> 6;
  int lane = threadIdx.x & 63;
  int row  = blockIdx.x * 4 + wave;          // < 8192
  const float* xr = x + (size_t)row * Dc;
  float4 v0 = ((const float4*)xr)[lane * 2];
  float4 v1 = ((const float4*)xr)[lane * 2 + 1];
  float sum = v0.x + v0.y + v0.z + v0.w + v1.x + v1.y + v1.z + v1.w;
  float sq  = v0.x*v0.x + v0.y*v0.y + v0.z*v0.z + v0.w*v0.w
            + v1.x*v1.x + v1.y*v1.y + v1.z*v1.z + v1.w*v1.w;
  #pragma unroll
  for (int off = 32; off > 0; off >>= 1) {
    sum += __shfl_xor(sum, off);
    sq  += __shfl_xor(sq, off);
  }
  float mu = sum * (1.0f / Dc);
  float rs = rsqrtf(sq * (1.0f / Dc) - mu * mu + LN_EPS);
  float4 g0 = ((const float4*)gamma)[lane * 2];
  float4 g1 = ((const float4*)gamma)[lane * 2 + 1];
  float4 b0 = ((const float4*)beta)[lane * 2];
  float4 b1 = ((const float4*)beta)[lane * 2 + 1];
  float4 o0, o1;
  o0.x = (v0.x - mu) * rs * g0.x + b0.x;
  o0.y = (v0.y - mu) * rs * g0.y + b0.y;
  o0.z = (v0.z - mu) * rs * g0.z + b0.z;
  o0.w = (v0.w - mu) * rs * g0.w + b0.w;
  o1.x = (v1.x - mu) * rs * g1.x + b1.x;
  o1.y = (v1.y - mu) * rs * g1.y + b1.y;
  o1.z = (v1.z - mu) * rs * g1.z + b1.z;
  o1.w = (v1.w - mu) * rs * g1.w + b1.w;
  float* xo = xn + (size_t)row * Dc;
  ((float4*)xo)[lane * 2]     = o0;
  ((float4*)xo)[lane * 2 + 1] = o1;
}

// ---------------------------------------------------------------------------
// Kernel 2/5: GEMM  out[n][e] = sum_d A[n][d] * W[e][d]
// MODE 0: out is [NTOK][Dc], adds residual res[n][e].
// MODE 1: out is Q/K/V layout [B][H][L][DH]; e = h*64+dh; n = b*L+l.
// Tile 64x64, BK=32, 256 threads, 4x4 per thread, float4 LDS reads.
// ---------------------------------------------------------------------------
template <int MODE>
__global__ __launch_bounds__(256) void gemm_nt(const float* __restrict__ A,
                                               const float* __restrict__ W,
                                               const float* __restrict__ res,
                                               float* __restrict__ out) {
  __shared__ float As[64][36];   // 36 = 32 + 4 pad, keeps float4 alignment
  __shared__ float Ws[64][36];
  int tid = threadIdx.x;
  int tx = tid & 15, ty = tid >> 4;
  int n0 = blockIdx.x * 64;
  int e0 = blockIdx.y * 64;
  float acc[4][4] = {};
  for (int k0 = 0; k0 < Dc; k0 += 32) {
    #pragma unroll
    for (int u = 0; u < 2; u++) {
      int idx = tid + u * 256;               // 0..511
      int r = idx >> 3;                      // 0..63
      int c = (idx & 7) << 2;                // 0,4,...,28
      *(float4*)&As[r][c] = *(const float4*)&A[(size_t)(n0 + r) * Dc + k0 + c];
      *(float4*)&Ws[r][c] = *(const float4*)&W[(size_t)(e0 + r) * Dc + k0 + c];
    }
    __syncthreads();
    #pragma unroll
    for (int kk = 0; kk < 32; kk += 4) {
      float a[4][4], w[4][4];
      #pragma unroll
      for (int i = 0; i < 4; i++) {
        float4 v = *(const float4*)&As[ty * 4 + i][kk];
        a[i][0] = v.x; a[i][1] = v.y; a[i][2] = v.z; a[i][3] = v.w;
      }
      #pragma unroll
      for (int j = 0; j < 4; j++) {
        float4 v = *(const float4*)&Ws[tx * 4 + j][kk];
        w[j][0] = v.x; w[j][1] = v.y; w[j][2] = v.z; w[j][3] = v.w;
      }
      #pragma unroll
      for (int t = 0; t < 4; t++)
        #pragma unroll
        for (int i = 0; i < 4; i++)
          #pragma unroll
          for (int j = 0; j < 4; j++)
            acc[i][j] += a[i][t] * w[j][t];
    }
    __syncthreads();
  }
  #pragma unroll
  for (int i = 0; i < 4; i++) {
    int n = n0 + ty * 4 + i;
    float4 v = make_float4(acc[i][0], acc[i][1], acc[i][2], acc[i][3]);
    if (MODE == 0) {
      size_t o = (size_t)n * Dc + e0 + tx * 4;
      float4 r4 = *(const float4*)&res[o];
      v.x += r4.x; v.y += r4.y; v.z += r4.z; v.w += r4.w;
      *(float4*)&out[o] = v;
    } else {
      int b = n >> 11;                 // L = 2048
      int l = n & (Lc - 1);
      int h = e0 >> 6;                 // e0 is a multiple of 64
      *(float4*)&out[(((size_t)(b * Hc + h)) * Lc + l) * DHc + tx * 4] = v;
    }
  }
}

// ---------------------------------------------------------------------------
// Kernel 3: V mean over L per (b,h,dh)  (for the all-masked uniform-softmax row)
// ---------------------------------------------------------------------------
__global__ __launch_bounds__(64) void vmean_kernel(const float* __restrict__ V,
                                                   float* __restrict__ vm) {
  int bh = blockIdx.x;
  int dh = threadIdx.x;
  const float* p = V + (size_t)bh * Lc * DHc + dh;
  float s = 0.f;
  for (int l = 0; l < Lc; l++) s += p[(size_t)l * DHc];
  vm[bh * DHc + dh] = s * (1.0f / Lc);
}

// ---------------------------------------------------------------------------
// Kernel 4: flash-style causal attention, fp32.
// Block = 256 threads handles a 64-row Q tile for one (b,h).
// Online softmax; P staged through LDS for the PV product.
// Output written in [B][L][H*DH] (= [NTOK][Dc]) layout for the final GEMM.
// ---------------------------------------------------------------------------
__global__ __launch_bounds__(256) void attn_kernel(const float* __restrict__ Q,
                                                   const float* __restrict__ K,
                                                   const float* __restrict__ V,
                                                   const float* __restrict__ vmean,
                                                   const int* __restrict__ tok,
                                                   float* __restrict__ out) {
  __shared__ float Qs[64][68];
  __shared__ float Ks[64][68];
  __shared__ float Vs[64][68];
  __shared__ float Ps[64][68];
  int tid = threadIdx.x;
  int tx = tid & 15, ty = tid >> 4;
  // launch heavy (large q0) tiles first for load balance
  int q0 = (gridDim.x - 1 - blockIdx.x) * 64;
  int bh = blockIdx.y;
  int b = bh >> 3, h = bh & 7;
  const float* Qp = Q + ((size_t)bh * Lc + q0) * DHc;
  #pragma unroll
  for (int u = 0; u < 4; u++) {
    int idx = tid + u * 256;
    int r = idx >> 4, c = (idx & 15) << 2;
    *(float4*)&Qs[r][c] = *(const float4*)&Qp[(size_t)r * DHc + c];
  }
  float m[4], lsum[4];
  float acc[4][4] = {};
  int qrow[4];
  #pragma unroll
  for (int i = 0; i < 4; i++) { m[i] = -INFINITY; lsum[i] = 0.f; qrow[i] = q0 + ty * 4 + i; }
  const int* tb = tok + b * Lc;
  int ktmax = q0 >> 6;
  for (int kt = 0; kt <= ktmax; kt++) {
    int k0 = kt * 64;
    __syncthreads();   // previous PV / Qs-producer done before overwriting tiles
    const float* Kp = K + ((size_t)bh * Lc + k0) * DHc;
    const float* Vp = V + ((size_t)bh * Lc + k0) * DHc;
    #pragma unroll
    for (int u = 0; u < 4; u++) {
      int idx = tid + u * 256;
      int r = idx >> 4, c = (idx & 15) << 2;
      *(float4*)&Ks[r][c] = *(const float4*)&Kp[(size_t)r * DHc + c];
      *(float4*)&Vs[r][c] = *(const float4*)&Vp[(size_t)r * DHc + c];
    }
    __syncthreads();
    // S = Q @ K^T  (4x4 per thread)
    float s[4][4] = {};
    #pragma unroll
    for (int d4 = 0; d4 < DHc; d4 += 4) {
      float a[4][4], kk_[4][4];
      #pragma unroll
      for (int i = 0; i < 4; i++) {
        float4 v = *(const float4*)&Qs[ty * 4 + i][d4];
        a[i][0] = v.x; a[i][1] = v.y; a[i][2] = v.z; a[i][3] = v.w;
      }
      #pragma unroll
      for (int j = 0; j < 4; j++) {
        float4 v = *(const float4*)&Ks[tx * 4 + j][d4];
        kk_[j][0] = v.x; kk_[j][1] = v.y; kk_[j][2] = v.z; kk_[j][3] = v.w;
      }
      #pragma unroll
      for (int t = 0; t < 4; t++)
        #pragma unroll
        for (int i = 0; i < 4; i++)
          #pragma unroll
          for (int j = 0; j < 4; j++)
            s[i][j] += a[i][t] * kk_[j][t];
    }
    // mask + online softmax update
    bool pad[4];
    #pragma unroll
    for (int j = 0; j < 4; j++) pad[j] = (tb[k0 + tx * 4 + j] == 0);
    #pragma unroll
    for (int i = 0; i < 4; i++) {
      float mx = -INFINITY;
      #pragma unroll
      for (int j = 0; j < 4; j++) {
        int k = k0 + tx * 4 + j;
        float v = s[i][j] * 0.125f;                 // / sqrt(64)
        if (k > qrow[i] || pad[j]) v = -INFINITY;
        s[i][j] = v;
        mx = fmaxf(mx, v);
      }
      #pragma unroll
      for (int off = 1; off < 16; off <<= 1) mx = fmaxf(mx, __shfl_xor(mx, off));
      float nm = fmaxf(m[i], mx);
      float alpha;
      float rsum = 0.f;
      if (nm == -INFINITY) {          // still no valid key for this row
        alpha = 1.f;
        #pragma unroll
        for (int j = 0; j < 4; j++) s[i][j] = 0.f;
      } else {
        alpha = __expf(m[i] - nm);    // m == -inf -> 0
        #pragma unroll
        for (int j = 0; j < 4; j++) {
          float p = __expf(s[i][j] - nm);   // -inf -> 0
          s[i][j] = p;
          rsum += p;
        }
      }
      #pragma unroll
      for (int off = 1; off < 16; off <<= 1) rsum += __shfl_xor(rsum, off);
      lsum[i] = lsum[i] * alpha + rsum;
      m[i] = nm;
      #pragma unroll
      for (int j = 0; j < 4; j++) acc[i][j] *= alpha;
      *(float4*)&Ps[ty * 4 + i][tx * 4] = make_float4(s[i][0], s[i][1], s[i][2], s[i][3]);
    }
    __syncthreads();
    // O += P @ V
    #pragma unroll
    for (int kk = 0; kk < 64; kk += 4) {
      float pa[4][4];
      #pragma unroll
      for (int i = 0; i < 4; i++) {
        float4 v = *(const float4*)&Ps[ty * 4 + i][kk];
        pa[i][0] = v.x; pa[i][1] = v.y; pa[i][2] = v.z; pa[i][3] = v.w;
      }
      #pragma unroll
      for (int t = 0; t < 4; t++) {
        float4 bv = *(const float4*)&Vs[kk + t][tx * 4];
        float bb[4] = {bv.x, bv.y, bv.z, bv.w};
        #pragma unroll
        for (int i = 0; i < 4; i++)
          #pragma unroll
          for (int j = 0; j < 4; j++)
            acc[i][j] += pa[i][t] * bb[j];
      }
    }
  }
  // epilogue: normalize; all-masked rows get uniform mean of ALL V rows
  #pragma unroll
  for (int i = 0; i < 4; i++) {
    int q = qrow[i];
    float4 v;
    if (lsum[i] > 0.f) {
      float inv = 1.0f / lsum[i];
      v = make_float4(acc[i][0] * inv, acc[i][1] * inv, acc[i][2] * inv, acc[i][3] * inv);
    } else {
      v = *(const float4*)&vmean[bh * DHc + tx * 4];
    }
    *(float4*)&out[((size_t)(b * Lc + q)) * Dc + h * DHc + tx * 4] = v;
  }
}

// ---------------------------------------------------------------------------
// Launch
// ---------------------------------------------------------------------------
extern "C" void kernel_launch(void* const* d_in, const int* in_sizes, int n_in,
                              void* d_out, int out_size, void* d_ws, size_t ws_size,
                              hipStream_t stream) {
  const float* x     = (const float*)d_in[0];
  const int*   tok   = (const int*)d_in[1];   // JAX default config: int64 -> int32
  const float* Wq    = (const float*)d_in[2];
  const float* Wk    = (const float*)d_in[3];
  const float* Wv    = (const float*)d_in[4];
  const float* Wo    = (const float*)d_in[5];
  const float* gamma = (const float*)d_in[6];
  const float* beta  = (const float*)d_in[7];
  float* out = (float*)d_out;

  // workspace: 5 x 16MB + vmean (needs ~84 MB)
  const size_t SEG = (size_t)NTOK * Dc;      // 4,194,304 floats
  float* xn = (float*)d_ws;
  float* Qd = xn + SEG;
  float* Kd = Qd + SEG;
  float* Vd = Kd + SEG;
  float* ao = Vd + SEG;
  float* vm = ao + SEG;                      // Bc*Hc*DHc = 2048 floats

  ln_kernel<<<NTOK / 4, 256, 0, stream>>>(x, gamma, beta, xn);

  dim3 gg(NTOK / 64, Dc / 64);               // 128 x 8
  gemm_nt<1><<<gg, 256, 0, stream>>>(xn, Wq, nullptr, Qd);
  gemm_nt<1><<<gg, 256, 0, stream>>>(xn, Wk, nullptr, Kd);
  gemm_nt<1><<<gg, 256, 0, stream>>>(xn, Wv, nullptr, Vd);

  vmean_kernel<<<Bc * Hc, 64, 0, stream>>>(Vd, vm);

  dim3 ga(Lc / 64, Bc * Hc);                 // 32 x 32
  attn_kernel<<<ga, 256, 0, stream>>>(Qd, Kd, Vd, vm, tok, ao);

  gemm_nt<0><<<gg, 256, 0, stream>>>(ao, Wo, x, out);
}

// Round 2
// 220.088 us; speedup vs baseline: 12.7026x; 12.7026x over previous
//
#include <hip/hip_runtime.h>
#include <math.h>

typedef unsigned short u16;
typedef unsigned int u32;
typedef float f32x4 __attribute__((ext_vector_type(4)));
typedef __bf16 bf16x8 __attribute__((ext_vector_type(8)));

constexpr int Bc = 4, Lc = 2048, Dc = 512, Hc = 8, DHc = 64;
constexpr int NTOK = Bc * Lc;          // 8192
constexpr float LN_EPS = 1e-5f;
constexpr int KS = 72;                 // padded LDS row stride (elems, 144B = 9*16B)

__device__ inline u16 f2bf(float f) {  // round-to-nearest-even
  u32 u = __float_as_uint(f);
  u += 0x7fff + ((u >> 16) & 1);
  return (u16)(u >> 16);
}
__device__ inline u32 pack2(float a, float b) {
  return (u32)f2bf(a) | ((u32)f2bf(b) << 16);
}
__device__ inline float bf2f(u16 u) { return __uint_as_float((u32)u << 16); }

// ---------------------------------------------------------------------------
// fp32 -> bf16 weight conversion (512x512 each; grid 256 x 256thr, 4 elem/thr)
// ---------------------------------------------------------------------------
__global__ __launch_bounds__(256) void cvt_kernel(const float* __restrict__ src,
                                                  u16* __restrict__ dst) {
  int i = (blockIdx.x * 256 + threadIdx.x) * 4;
  float4 v = *(const float4*)&src[i];
  uint2 r;
  r.x = pack2(v.x, v.y);
  r.y = pack2(v.z, v.w);
  *(uint2*)&dst[i] = r;
}

// ---------------------------------------------------------------------------
// LayerNorm: one wave per row of 512, bf16 output
// ---------------------------------------------------------------------------
__global__ __launch_bounds__(256) void ln_kernel(const float* __restrict__ x,
                                                 const float* __restrict__ gamma,
                                                 const float* __restrict__ beta,
                                                 u16* __restrict__ xn) {
  int wave = threadIdx.x >> 6;
  int lane = threadIdx.x & 63;
  int row  = blockIdx.x * 4 + wave;
  const float* xr = x + (size_t)row * Dc;
  float4 v0 = ((const float4*)xr)[lane * 2];
  float4 v1 = ((const float4*)xr)[lane * 2 + 1];
  float sum = v0.x + v0.y + v0.z + v0.w + v1.x + v1.y + v1.z + v1.w;
  float sq  = v0.x*v0.x + v0.y*v0.y + v0.z*v0.z + v0.w*v0.w
            + v1.x*v1.x + v1.y*v1.y + v1.z*v1.z + v1.w*v1.w;
  #pragma unroll
  for (int off = 32; off > 0; off >>= 1) {
    sum += __shfl_xor(sum, off);
    sq  += __shfl_xor(sq, off);
  }
  float mu = sum * (1.0f / Dc);
  float rs = rsqrtf(sq * (1.0f / Dc) - mu * mu + LN_EPS);
  float4 g0 = ((const float4*)gamma)[lane * 2];
  float4 g1 = ((const float4*)gamma)[lane * 2 + 1];
  float4 b0 = ((const float4*)beta)[lane * 2];
  float4 b1 = ((const float4*)beta)[lane * 2 + 1];
  uint4 ov;
  ov.x = pack2((v0.x - mu) * rs * g0.x + b0.x, (v0.y - mu) * rs * g0.y + b0.y);
  ov.y = pack2((v0.z - mu) * rs * g0.z + b0.z, (v0.w - mu) * rs * g0.w + b0.w);
  ov.z = pack2((v1.x - mu) * rs * g1.x + b1.x, (v1.y - mu) * rs * g1.y + b1.y);
  ov.w = pack2((v1.z - mu) * rs * g1.z + b1.z, (v1.w - mu) * rs * g1.w + b1.w);
  *(uint4*)&xn[(size_t)row * Dc + lane * 8] = ov;
}

// ---------------------------------------------------------------------------
// bf16 MFMA GEMM: C[n][e] = sum_d A[n][d] * W[e][d]   (both row-major, k-contig)
// 128x128 tile, BK=64, 256 thr (4 waves, 2x2), 4x4 16x16 frags per wave.
// MODE 0: fp32 out [NTOK][Dc] + residual.  MODE 1: bf16 out in [B][H][L][DH].
// ---------------------------------------------------------------------------
template <int MODE>
__global__ __launch_bounds__(256) void gemm_bf16(const u16* __restrict__ A,
                                                 const u16* __restrict__ W,
                                                 const float* __restrict__ res,
                                                 void* __restrict__ outp) {
  __shared__ u16 As[128 * KS];
  __shared__ u16 Bs[128 * KS];
  int tid = threadIdx.x;
  int lane = tid & 63;
  int w = tid >> 6;
  int wr = w >> 1, wc = w & 1;
  int cc = lane & 15, rb = lane >> 4;
  int n0 = blockIdx.x * 128;
  int e0 = blockIdx.y * 128;
  f32x4 acc[4][4] = {};
  for (int k0 = 0; k0 < Dc; k0 += 64) {
    #pragma unroll
    for (int u = 0; u < 4; u++) {
      int idx = u * 256 + tid;             // 0..1023
      int row = idx >> 3;                  // 0..127
      int col = (idx & 7) << 3;            // 0..56
      *(uint4*)&As[row * KS + col] = *(const uint4*)&A[(size_t)(n0 + row) * Dc + k0 + col];
      *(uint4*)&Bs[row * KS + col] = *(const uint4*)&W[(size_t)(e0 + row) * Dc + k0 + col];
    }
    __syncthreads();
    #pragma unroll
    for (int kk = 0; kk < 64; kk += 32) {
      bf16x8 aF[4], bF[4];
      #pragma unroll
      for (int m = 0; m < 4; m++)
        aF[m] = *(bf16x8*)&As[(wr * 64 + m * 16 + cc) * KS + kk + rb * 8];
      #pragma unroll
      for (int n = 0; n < 4; n++)
        bF[n] = *(bf16x8*)&Bs[(wc * 64 + n * 16 + cc) * KS + kk + rb * 8];
      #pragma unroll
      for (int m = 0; m < 4; m++)
        #pragma unroll
        for (int n = 0; n < 4; n++)
          acc[m][n] = __builtin_amdgcn_mfma_f32_16x16x32_bf16(aF[m], bF[n], acc[m][n], 0, 0, 0);
    }
    __syncthreads();
  }
  #pragma unroll
  for (int m = 0; m < 4; m++) {
    #pragma unroll
    for (int n = 0; n < 4; n++) {
      #pragma unroll
      for (int j = 0; j < 4; j++) {
        int r = n0 + wr * 64 + m * 16 + rb * 4 + j;   // global row n
        int c = e0 + wc * 64 + n * 16 + cc;           // global col e
        float v = acc[m][n][j];
        if (MODE == 0) {
          float* out = (float*)outp;
          size_t o = (size_t)r * Dc + c;
          out[o] = v + res[o];
        } else {
          u16* out = (u16*)outp;
          int b = r >> 11, ll = r & (Lc - 1);
          int h = c >> 6, dh = c & 63;
          out[(((size_t)(b * Hc + h)) * Lc + ll) * DHc + dh] = f2bf(v);
        }
      }
    }
  }
}

// ---------------------------------------------------------------------------
// V mean over L per (b,h) from bf16 V  (all-masked fallback row)
// ---------------------------------------------------------------------------
__global__ __launch_bounds__(64) void vmean_kernel(const u16* __restrict__ V,
                                                   float* __restrict__ vm) {
  int bh = blockIdx.x;
  int l = threadIdx.x;
  const u16* base = V + (size_t)bh * Lc * DHc;
  float s[8] = {};
  for (int r0 = 0; r0 < Lc; r0 += 8) {
    int row = r0 + (l >> 3);
    uint4 v = *(const uint4*)&base[(size_t)row * DHc + (l & 7) * 8];
    const u32* pu = (const u32*)&v;
    #pragma unroll
    for (int p = 0; p < 4; p++) {
      s[2 * p]     += bf2f((u16)(pu[p] & 0xffff));
      s[2 * p + 1] += bf2f((u16)(pu[p] >> 16));
    }
  }
  #pragma unroll
  for (int off = 8; off < 64; off <<= 1)
    #pragma unroll
    for (int j = 0; j < 8; j++) s[j] += __shfl_xor(s[j], off);
  if (l < 8) {
    #pragma unroll
    for (int j = 0; j < 8; j++) vm[bh * DHc + l * 8 + j] = s[j] * (1.0f / Lc);
  }
}

// ---------------------------------------------------------------------------
// Flash attention, bf16 MFMA. 4 waves x 16 q-rows, KV tile = 64.
// ---------------------------------------------------------------------------
__global__ __launch_bounds__(256) void attn_bf16(const u16* __restrict__ Q,
                                                 const u16* __restrict__ K,
                                                 const u16* __restrict__ V,
                                                 const float* __restrict__ vmean,
                                                 const int* __restrict__ tok,
                                                 u16* __restrict__ out) {
  __shared__ u16 Ks[64 * KS];
  __shared__ u16 Vt[64 * KS];          // transposed: Vt[d][k]
  __shared__ u16 Ps[4][16 * KS];       // per-wave P tile
  int tid = threadIdx.x;
  int lane = tid & 63;
  int w = tid >> 6;
  int cc = lane & 15, rb = lane >> 4;
  int q0 = (int)(gridDim.x - 1 - blockIdx.x) * 64;   // heavy tiles first
  int bh = blockIdx.y;
  int b = bh >> 3, h = bh & 7;

  // Q fragments pinned in registers
  bf16x8 qF0, qF1;
  {
    const u16* Qp = Q + ((size_t)bh * Lc + q0 + w * 16 + cc) * DHc + rb * 8;
    qF0 = *(const bf16x8*)&Qp[0];
    qF1 = *(const bf16x8*)&Qp[32];
  }
  float mrow[4], lrow[4];
  f32x4 o[4] = {};
  int qrow[4];
  #pragma unroll
  for (int j = 0; j < 4; j++) {
    mrow[j] = -INFINITY; lrow[j] = 0.f;
    qrow[j] = q0 + w * 16 + rb * 4 + j;
  }
  const int* tb = tok + b * Lc;
  int ktmax = q0 >> 6;
  for (int kt = 0; kt <= ktmax; kt++) {
    int k0 = kt * 64;
    __syncthreads();                   // prev tile fully consumed
    const u16* Kp = K + ((size_t)bh * Lc + k0) * DHc;
    const u16* Vp = V + ((size_t)bh * Lc + k0) * DHc;
    #pragma unroll
    for (int u = 0; u < 2; u++) {      // K tile: row-major copy
      int idx = u * 256 + tid;
      int row = idx >> 3;
      int col = (idx & 7) << 3;
      *(uint4*)&Ks[row * KS + col] = *(const uint4*)&Kp[(size_t)row * DHc + col];
    }
    #pragma unroll
    for (int u = 0; u < 2; u++) {      // V tile transposed: coalesced 2B reads
      int g = w * 2 + u;               // k-group 0..7
      union { u16 us[8]; uint4 v; } pk;
      #pragma unroll
      for (int e = 0; e < 8; e++) pk.us[e] = Vp[(size_t)(g * 8 + e) * DHc + lane];
      *(uint4*)&Vt[lane * KS + g * 8] = pk.v;
    }
    __syncthreads();
    // S = Q K^T  (4 col-frags of 16 keys)
    f32x4 s[4];
    #pragma unroll
    for (int c = 0; c < 4; c++) {
      bf16x8 kF0 = *(bf16x8*)&Ks[(c * 16 + cc) * KS + rb * 8];
      bf16x8 kF1 = *(bf16x8*)&Ks[(c * 16 + cc) * KS + 32 + rb * 8];
      f32x4 z = {};
      z = __builtin_amdgcn_mfma_f32_16x16x32_bf16(qF0, kF0, z, 0, 0, 0);
      s[c] = __builtin_amdgcn_mfma_f32_16x16x32_bf16(qF1, kF1, z, 0, 0, 0);
    }
    // mask + online softmax (row r = qrow[j], col = k0 + c*16 + cc)
    bool padc[4]; int keyc[4];
    #pragma unroll
    for (int c = 0; c < 4; c++) {
      keyc[c] = k0 + c * 16 + cc;
      padc[c] = (tb[keyc[c]] == 0);
    }
    float sv[4][4];
    #pragma unroll
    for (int c = 0; c < 4; c++)
      #pragma unroll
      for (int j = 0; j < 4; j++) {
        float v = s[c][j] * 0.125f;
        if (keyc[c] > qrow[j] || padc[c]) v = -INFINITY;
        sv[c][j] = v;
      }
    float nm[4], alpha[4], rsum[4], pb[4][4];
    #pragma unroll
    for (int j = 0; j < 4; j++) {
      float mx = fmaxf(fmaxf(sv[0][j], sv[1][j]), fmaxf(sv[2][j], sv[3][j]));
      #pragma unroll
      for (int off = 1; off < 16; off <<= 1) mx = fmaxf(mx, __shfl_xor(mx, off));
      nm[j] = fmaxf(mrow[j], mx);
      rsum[j] = 0.f;
    }
    #pragma unroll
    for (int c = 0; c < 4; c++)
      #pragma unroll
      for (int j = 0; j < 4; j++) {
        float p = (nm[j] == -INFINITY) ? 0.f : __expf(sv[c][j] - nm[j]);
        pb[c][j] = p;
        rsum[j] += p;
      }
    #pragma unroll
    for (int j = 0; j < 4; j++) {
      #pragma unroll
      for (int off = 1; off < 16; off <<= 1) rsum[j] += __shfl_xor(rsum[j], off);
      alpha[j] = (nm[j] == -INFINITY) ? 1.f : __expf(mrow[j] - nm[j]);
      lrow[j] = lrow[j] * alpha[j] + rsum[j];
      mrow[j] = nm[j];
    }
    #pragma unroll
    for (int cd = 0; cd < 4; cd++)
      #pragma unroll
      for (int j = 0; j < 4; j++)
        o[cd][j] *= alpha[j];
    // P -> per-wave LDS (bf16)
    #pragma unroll
    for (int c = 0; c < 4; c++)
      #pragma unroll
      for (int j = 0; j < 4; j++)
        Ps[w][(rb * 4 + j) * KS + c * 16 + cc] = f2bf(pb[c][j]);
    asm volatile("s_waitcnt lgkmcnt(0)" ::: "memory");   // wave-local RAW on Ps
    // O += P @ V   (A = P row cc, B = Vt row d)
    bf16x8 aP0 = *(bf16x8*)&Ps[w][cc * KS + rb * 8];
    bf16x8 aP1 = *(bf16x8*)&Ps[w][cc * KS + 32 + rb * 8];
    #pragma unroll
    for (int cd = 0; cd < 4; cd++) {
      bf16x8 bV0 = *(bf16x8*)&Vt[(cd * 16 + cc) * KS + rb * 8];
      bf16x8 bV1 = *(bf16x8*)&Vt[(cd * 16 + cc) * KS + 32 + rb * 8];
      o[cd] = __builtin_amdgcn_mfma_f32_16x16x32_bf16(aP0, bV0, o[cd], 0, 0, 0);
      o[cd] = __builtin_amdgcn_mfma_f32_16x16x32_bf16(aP1, bV1, o[cd], 0, 0, 0);
    }
  }
  // epilogue: normalize; all-masked rows -> uniform mean of ALL V rows
  #pragma unroll
  for (int j = 0; j < 4; j++) {
    int q = qrow[j];
    bool fb = !(lrow[j] > 0.f);
    float inv = fb ? 0.f : 1.0f / lrow[j];
    #pragma unroll
    for (int cd = 0; cd < 4; cd++) {
      float v = fb ? vmean[bh * DHc + cd * 16 + cc] : o[cd][j] * inv;
      out[((size_t)(b * Lc + q)) * Dc + h * DHc + cd * 16 + cc] = f2bf(v);
    }
  }
}

// ---------------------------------------------------------------------------
// Launch
// ---------------------------------------------------------------------------
extern "C" void kernel_launch(void* const* d_in, const int* in_sizes, int n_in,
                              void* d_out, int out_size, void* d_ws, size_t ws_size,
                              hipStream_t stream) {
  const float* x     = (const float*)d_in[0];
  const int*   tok   = (const int*)d_in[1];
  const float* Wq    = (const float*)d_in[2];
  const float* Wk    = (const float*)d_in[3];
  const float* Wv    = (const float*)d_in[4];
  const float* Wo    = (const float*)d_in[5];
  const float* gamma = (const float*)d_in[6];
  const float* beta  = (const float*)d_in[7];
  float* out = (float*)d_out;

  const size_t SEG = (size_t)NTOK * Dc;     // 4,194,304 elems
  const size_t WSEG = (size_t)Dc * Dc;      // 262,144 elems
  u16* xn  = (u16*)d_ws;
  u16* Qd  = xn + SEG;
  u16* Kd  = Qd + SEG;
  u16* Vd  = Kd + SEG;
  u16* ao  = Vd + SEG;
  u16* Wqb = ao + SEG;
  u16* Wkb = Wqb + WSEG;
  u16* Wvb = Wkb + WSEG;
  u16* Wob = Wvb + WSEG;
  float* vm = (float*)(Wob + WSEG);

  cvt_kernel<<<256, 256, 0, stream>>>(Wq, Wqb);
  cvt_kernel<<<256, 256, 0, stream>>>(Wk, Wkb);
  cvt_kernel<<<256, 256, 0, stream>>>(Wv, Wvb);
  cvt_kernel<<<256, 256, 0, stream>>>(Wo, Wob);

  ln_kernel<<<NTOK / 4, 256, 0, stream>>>(x, gamma, beta, xn);

  dim3 gg(NTOK / 128, Dc / 128);            // 64 x 4
  gemm_bf16<1><<<gg, 256, 0, stream>>>(xn, Wqb, nullptr, Qd);
  gemm_bf16<1><<<gg, 256, 0, stream>>>(xn, Wkb, nullptr, Kd);
  gemm_bf16<1><<<gg, 256, 0, stream>>>(xn, Wvb, nullptr, Vd);

  vmean_kernel<<<Bc * Hc, 64, 0, stream>>>(Vd, vm);

  dim3 ga(Lc / 64, Bc * Hc);                // 32 x 32
  attn_bf16<<<ga, 256, 0, stream>>>(Qd, Kd, Vd, vm, tok, ao);

  gemm_bf16<0><<<gg, 256, 0, stream>>>(ao, Wob, x, out);
}

// Round 4
// 159.494 us; speedup vs baseline: 17.5285x; 1.3799x over previous
//
#include <hip/hip_runtime.h>
#include <math.h>

typedef unsigned short u16;
typedef unsigned int u32;
typedef unsigned long long u64;
typedef float f32x4 __attribute__((ext_vector_type(4)));
typedef __bf16 bf16x8 __attribute__((ext_vector_type(8)));

constexpr int Bc = 4, Lc = 2048, Dc = 512, Hc = 8, DHc = 64;
constexpr int NTOK = Bc * Lc;          // 8192
constexpr float LN_EPS = 1e-5f;
constexpr int KS = 72;                 // gemm LDS row stride (elems; 144B = 16B-aligned)
constexpr int PS = 72;                 // attn P-scratch row stride

__device__ inline u16 f2bf(float f) {  // round-to-nearest-even
  u32 u = __float_as_uint(f);
  u += 0x7fff + ((u >> 16) & 1);
  return (u16)(u >> 16);
}
__device__ inline u32 pack2(float a, float b) {
  return (u32)f2bf(a) | ((u32)f2bf(b) << 16);
}

// ---------------------------------------------------------------------------
// fp32 -> bf16 weight conversion
// ---------------------------------------------------------------------------
__global__ __launch_bounds__(256) void cvt_kernel(const float* __restrict__ src,
                                                  u16* __restrict__ dst) {
  int i = (blockIdx.x * 256 + threadIdx.x) * 4;
  float4 v = *(const float4*)&src[i];
  uint2 r;
  r.x = pack2(v.x, v.y);
  r.y = pack2(v.z, v.w);
  *(uint2*)&dst[i] = r;
}

// ---------------------------------------------------------------------------
// LayerNorm: one wave per row of 512, bf16 output
// ---------------------------------------------------------------------------
__global__ __launch_bounds__(256) void ln_kernel(const float* __restrict__ x,
                                                 const float* __restrict__ gamma,
                                                 const float* __restrict__ beta,
                                                 u16* __restrict__ xn) {
  int wave = threadIdx.x >> 6;
  int lane = threadIdx.x & 63;
  int row  = blockIdx.x * 4 + wave;
  const float* xr = x + (size_t)row * Dc;
  float4 v0 = ((const float4*)xr)[lane * 2];
  float4 v1 = ((const float4*)xr)[lane * 2 + 1];
  float sum = v0.x + v0.y + v0.z + v0.w + v1.x + v1.y + v1.z + v1.w;
  float sq  = v0.x*v0.x + v0.y*v0.y + v0.z*v0.z + v0.w*v0.w
            + v1.x*v1.x + v1.y*v1.y + v1.z*v1.z + v1.w*v1.w;
  #pragma unroll
  for (int off = 32; off > 0; off >>= 1) {
    sum += __shfl_xor(sum, off);
    sq  += __shfl_xor(sq, off);
  }
  float mu = sum * (1.0f / Dc);
  float rs = rsqrtf(sq * (1.0f / Dc) - mu * mu + LN_EPS);
  float4 g0 = ((const float4*)gamma)[lane * 2];
  float4 g1 = ((const float4*)gamma)[lane * 2 + 1];
  float4 b0 = ((const float4*)beta)[lane * 2];
  float4 b1 = ((const float4*)beta)[lane * 2 + 1];
  uint4 ov;
  ov.x = pack2((v0.x - mu) * rs * g0.x + b0.x, (v0.y - mu) * rs * g0.y + b0.y);
  ov.y = pack2((v0.z - mu) * rs * g0.z + b0.z, (v0.w - mu) * rs * g0.w + b0.w);
  ov.z = pack2((v1.x - mu) * rs * g1.x + b1.x, (v1.y - mu) * rs * g1.y + b1.y);
  ov.w = pack2((v1.z - mu) * rs * g1.z + b1.z, (v1.w - mu) * rs * g1.w + b1.w);
  *(uint4*)&xn[(size_t)row * Dc + lane * 8] = ov;
}

// ---------------------------------------------------------------------------
// bf16 MFMA GEMM: C[n][e] = sum_d A[n][d] * W[e][d]
// MODE 0: fp32 out [NTOK][Dc] + residual.
// MODE 1: bf16 out, [B][H][L][DH] layout.
// MODE 2: bf16 out, TRANSPOSED [B][H][DH][L] layout + atomic column-sum -> vm.
// ---------------------------------------------------------------------------
template <int MODE>
__global__ __launch_bounds__(256) void gemm_bf16(const u16* __restrict__ A,
                                                 const u16* __restrict__ W,
                                                 const float* __restrict__ res,
                                                 void* __restrict__ outp,
                                                 float* __restrict__ vm) {
  __shared__ u16 As[128 * KS];
  __shared__ u16 Bs[128 * KS];
  int tid = threadIdx.x;
  int lane = tid & 63;
  int w = tid >> 6;
  int wr = w >> 1, wc = w & 1;
  int cc = lane & 15, rb = lane >> 4;
  int n0 = blockIdx.x * 128;
  int e0 = blockIdx.y * 128;
  f32x4 acc[4][4] = {};
  for (int k0 = 0; k0 < Dc; k0 += 64) {
    #pragma unroll
    for (int u = 0; u < 4; u++) {
      int idx = u * 256 + tid;
      int row = idx >> 3;
      int col = (idx & 7) << 3;
      *(uint4*)&As[row * KS + col] = *(const uint4*)&A[(size_t)(n0 + row) * Dc + k0 + col];
      *(uint4*)&Bs[row * KS + col] = *(const uint4*)&W[(size_t)(e0 + row) * Dc + k0 + col];
    }
    __syncthreads();
    #pragma unroll
    for (int kk = 0; kk < 64; kk += 32) {
      bf16x8 aF[4], bF[4];
      #pragma unroll
      for (int m = 0; m < 4; m++)
        aF[m] = *(bf16x8*)&As[(wr * 64 + m * 16 + cc) * KS + kk + rb * 8];
      #pragma unroll
      for (int n = 0; n < 4; n++)
        bF[n] = *(bf16x8*)&Bs[(wc * 64 + n * 16 + cc) * KS + kk + rb * 8];
      #pragma unroll
      for (int m = 0; m < 4; m++)
        #pragma unroll
        for (int n = 0; n < 4; n++)
          acc[m][n] = __builtin_amdgcn_mfma_f32_16x16x32_bf16(aF[m], bF[n], acc[m][n], 0, 0, 0);
    }
    __syncthreads();
  }
  if (MODE == 2) {
    u16* outv = (u16*)outp;
    int bb = n0 >> 11;
    float cp[4] = {0.f, 0.f, 0.f, 0.f};
    #pragma unroll
    for (int m = 0; m < 4; m++) {
      int l0 = (n0 + wr * 64 + m * 16 + rb * 4) & (Lc - 1);
      #pragma unroll
      for (int n = 0; n < 4; n++) {
        int c = e0 + wc * 64 + n * 16 + cc;
        uint2 wv;
        wv.x = pack2(acc[m][n][0], acc[m][n][1]);
        wv.y = pack2(acc[m][n][2], acc[m][n][3]);
        *(uint2*)&outv[((size_t)(bb * Hc + (c >> 6)) * DHc + (c & 63)) * Lc + l0] = wv;
        cp[n] += (acc[m][n][0] + acc[m][n][1]) + (acc[m][n][2] + acc[m][n][3]);
      }
    }
    #pragma unroll
    for (int n = 0; n < 4; n++) {
      cp[n] += __shfl_xor(cp[n], 16);
      cp[n] += __shfl_xor(cp[n], 32);
    }
    if (lane < 16) {
      #pragma unroll
      for (int n = 0; n < 4; n++) {
        int c = e0 + wc * 64 + n * 16 + cc;
        atomicAdd(&vm[(bb * Hc + (c >> 6)) * DHc + (c & 63)], cp[n]);
      }
    }
  } else {
    #pragma unroll
    for (int m = 0; m < 4; m++) {
      #pragma unroll
      for (int n = 0; n < 4; n++) {
        #pragma unroll
        for (int j = 0; j < 4; j++) {
          int r = n0 + wr * 64 + m * 16 + rb * 4 + j;
          int c = e0 + wc * 64 + n * 16 + cc;
          float v = acc[m][n][j];
          if (MODE == 0) {
            float* out = (float*)outp;
            size_t o = (size_t)r * Dc + c;
            out[o] = v + res[o];
          } else {
            u16* out = (u16*)outp;
            int b = r >> 11, ll = r & (Lc - 1);
            out[(((size_t)(b * Hc + (c >> 6))) * Lc + ll) * DHc + (c & 63)] = f2bf(v);
          }
        }
      }
    }
  }
}

// ---------------------------------------------------------------------------
// Flash attention v2: 1 wave/block, QBLK=32, KVBLK=64, swapped QK^T,
// no __syncthreads, K/V direct from global (L2-resident), P via 4.6KB LDS.
// ---------------------------------------------------------------------------
__global__ __launch_bounds__(64) void attn2(const u16* __restrict__ Q,
                                            const u16* __restrict__ K,
                                            const u16* __restrict__ VT,
                                            const float* __restrict__ vm,
                                            const int* __restrict__ tok,
                                            u16* __restrict__ out) {
  __shared__ u16 Ps[32 * PS];
  int lane = threadIdx.x;
  int cc = lane & 15, rb = lane >> 4;
  int bh = blockIdx.x;                               // fast dim: heads spread over XCDs
  int qt = (int)gridDim.y - 1 - (int)blockIdx.y;     // heavy q-tiles dispatched first
  int q0 = qt * 32;
  int b = bh >> 3, h = bh & 7;
  const u16* Qb = Q + (size_t)bh * Lc * DHc;
  const u16* Kb = K + (size_t)bh * Lc * DHc;
  const u16* Vb = VT + (size_t)bh * DHc * Lc;
  const int* tb = tok + b * Lc;

  // Q fragments (B-operand): lane holds Q[q0+qb*16+cc][kc*32+rb*8 ..+7]
  bf16x8 qF[2][2];
  #pragma unroll
  for (int qb = 0; qb < 2; qb++)
    #pragma unroll
    for (int kc = 0; kc < 2; kc++)
      qF[qb][kc] = *(const bf16x8*)&Qb[(size_t)(q0 + qb * 16 + cc) * DHc + kc * 32 + rb * 8];

  float mrow[2] = {-INFINITY, -INFINITY};
  float lrow[2] = {0.f, 0.f};
  f32x4 acc[2][4] = {};                              // O^T: [qb][d0], q=cc, d=d0*16+rb*4+j

  int nfull = q0 >> 6;                               // last tile (kt==nfull) is boundary
  for (int kt = 0; kt <= nfull; kt++) {
    int k0 = kt * 64;
    bool bnd = (kt == nfull);
    u64 pm = __ballot(tb[k0 + lane] == 0);           // pad bitmask for 64 keys

    // S^T = K·Q^T : rows k, cols q
    f32x4 sq[2][4] = {};
    #pragma unroll
    for (int c = 0; c < 4; c++) {
      const u16* kp = &Kb[(size_t)(k0 + c * 16 + cc) * DHc + rb * 8];
      bf16x8 kf0 = *(const bf16x8*)kp;
      bf16x8 kf1 = *(const bf16x8*)(kp + 32);
      #pragma unroll
      for (int qb = 0; qb < 2; qb++) {
        sq[qb][c] = __builtin_amdgcn_mfma_f32_16x16x32_bf16(kf0, qF[qb][0], sq[qb][c], 0, 0, 0);
        sq[qb][c] = __builtin_amdgcn_mfma_f32_16x16x32_bf16(kf1, qF[qb][1], sq[qb][c], 0, 0, 0);
      }
    }
    // scale + pad bias (k = c*16 + rb*4 + j)
    #pragma unroll
    for (int c = 0; c < 4; c++) {
      u32 smr = (((u32)(pm >> (c * 16)) & 0xffffu) >> (rb * 4));
      f32x4 bs;
      #pragma unroll
      for (int j = 0; j < 4; j++) bs[j] = ((smr >> j) & 1) ? -INFINITY : 0.0f;
      #pragma unroll
      for (int qb = 0; qb < 2; qb++)
        #pragma unroll
        for (int j = 0; j < 4; j++)
          sq[qb][c][j] = sq[qb][c][j] * 0.125f + bs[j];
    }
    if (bnd) {                                       // causal only on the boundary tile
      #pragma unroll
      for (int qb = 0; qb < 2; qb++) {
        int qrel = q0 + qb * 16 + cc - k0;
        #pragma unroll
        for (int c = 0; c < 4; c++)
          #pragma unroll
          for (int j = 0; j < 4; j++)
            if (c * 16 + rb * 4 + j > qrel) sq[qb][c][j] = -INFINITY;
      }
    }
    // online softmax (row q = cc is lane-local; reduce over rb via 2 shuffles)
    #pragma unroll
    for (int qb = 0; qb < 2; qb++) {
      float m0 = fmaxf(fmaxf(sq[qb][0][0], sq[qb][0][1]), fmaxf(sq[qb][0][2], sq[qb][0][3]));
      float m1 = fmaxf(fmaxf(sq[qb][1][0], sq[qb][1][1]), fmaxf(sq[qb][1][2], sq[qb][1][3]));
      float m2 = fmaxf(fmaxf(sq[qb][2][0], sq[qb][2][1]), fmaxf(sq[qb][2][2], sq[qb][2][3]));
      float m3 = fmaxf(fmaxf(sq[qb][3][0], sq[qb][3][1]), fmaxf(sq[qb][3][2], sq[qb][3][3]));
      float mx = fmaxf(fmaxf(m0, m1), fmaxf(m2, m3));
      mx = fmaxf(mx, __shfl_xor(mx, 16));
      mx = fmaxf(mx, __shfl_xor(mx, 32));
      float nm = fmaxf(mrow[qb], mx);
      float nm2 = fmaxf(nm, -1e30f);                 // finite clamp: kills all NaN paths
      float alpha = __expf(mrow[qb] - nm2);          // mrow=-inf -> 0 (state is zero anyway)
      mrow[qb] = nm;
      float rs = 0.f;
      u32 pw[8];
      #pragma unroll
      for (int c = 0; c < 4; c++) {
        f32x4 p;
        #pragma unroll
        for (int j = 0; j < 4; j++) p[j] = __expf(sq[qb][c][j] - nm2);
        rs += (p[0] + p[1]) + (p[2] + p[3]);
        pw[c * 2]     = pack2(p[0], p[1]);
        pw[c * 2 + 1] = pack2(p[2], p[3]);
      }
      rs += __shfl_xor(rs, 16);
      rs += __shfl_xor(rs, 32);
      lrow[qb] = lrow[qb] * alpha + rs;
      #pragma unroll
      for (int d0 = 0; d0 < 4; d0++)
        #pragma unroll
        for (int j = 0; j < 4; j++)
          acc[qb][d0][j] *= alpha;
      // P^T -> Ps[q][k] (rows q = qb*16+cc, k pairs contiguous)
      u32* pr = (u32*)&Ps[(qb * 16 + cc) * PS];
      #pragma unroll
      for (int c = 0; c < 4; c++) {
        pr[(c * 16 + rb * 4) >> 1]       = pw[c * 2];
        pr[((c * 16 + rb * 4) >> 1) + 1] = pw[c * 2 + 1];
      }
    }
    asm volatile("s_waitcnt lgkmcnt(0)" ::: "memory");   // wave-local RAW on Ps
    __builtin_amdgcn_sched_barrier(0);                   // rule #18: pin MFMA after wait
    // O^T += V^T · P^T
    #pragma unroll
    for (int kc = 0; kc < 2; kc++) {
      bf16x8 pF0 = *(bf16x8*)&Ps[(size_t)cc * PS + kc * 32 + rb * 8];
      bf16x8 pF1 = *(bf16x8*)&Ps[(size_t)(16 + cc) * PS + kc * 32 + rb * 8];
      #pragma unroll
      for (int d0 = 0; d0 < 4; d0++) {
        bf16x8 vf = *(const bf16x8*)&Vb[(size_t)(d0 * 16 + cc) * Lc + k0 + kc * 32 + rb * 8];
        acc[0][d0] = __builtin_amdgcn_mfma_f32_16x16x32_bf16(vf, pF0, acc[0][d0], 0, 0, 0);
        acc[1][d0] = __builtin_amdgcn_mfma_f32_16x16x32_bf16(vf, pF1, acc[1][d0], 0, 0, 0);
      }
    }
  }
  // epilogue: normalize; all-masked rows -> uniform mean of ALL V rows
  #pragma unroll
  for (int qb = 0; qb < 2; qb++) {
    int q = q0 + qb * 16 + cc;
    bool ok = lrow[qb] > 0.f;
    float inv = ok ? 1.0f / lrow[qb] : 0.f;
    #pragma unroll
    for (int d0 = 0; d0 < 4; d0++) {
      f32x4 o;
      #pragma unroll
      for (int j = 0; j < 4; j++) o[j] = acc[qb][d0][j] * inv;
      if (!ok) {
        #pragma unroll
        for (int j = 0; j < 4; j++)
          o[j] = vm[bh * DHc + d0 * 16 + rb * 4 + j] * (1.0f / Lc);
      }
      uint2 wv;
      wv.x = pack2(o[0], o[1]);
      wv.y = pack2(o[2], o[3]);
      *(uint2*)&out[((size_t)(b * Lc + q)) * Dc + h * DHc + d0 * 16 + rb * 4] = wv;
    }
  }
}

// ---------------------------------------------------------------------------
// Launch
// ---------------------------------------------------------------------------
extern "C" void kernel_launch(void* const* d_in, const int* in_sizes, int n_in,
                              void* d_out, int out_size, void* d_ws, size_t ws_size,
                              hipStream_t stream) {
  const float* x     = (const float*)d_in[0];
  const int*   tok   = (const int*)d_in[1];
  const float* Wq    = (const float*)d_in[2];
  const float* Wk    = (const float*)d_in[3];
  const float* Wv    = (const float*)d_in[4];
  const float* Wo    = (const float*)d_in[5];
  const float* gamma = (const float*)d_in[6];
  const float* beta  = (const float*)d_in[7];
  float* out = (float*)d_out;

  const size_t SEG = (size_t)NTOK * Dc;
  const size_t WSEG = (size_t)Dc * Dc;
  u16* xn  = (u16*)d_ws;
  u16* Qd  = xn + SEG;
  u16* Kd  = Qd + SEG;
  u16* VT  = Kd + SEG;
  u16* ao  = VT + SEG;
  u16* Wqb = ao + SEG;
  u16* Wkb = Wqb + WSEG;
  u16* Wvb = Wkb + WSEG;
  u16* Wob = Wvb + WSEG;
  float* vm = (float*)(Wob + WSEG);

  hipMemsetAsync(vm, 0, (size_t)Bc * Hc * DHc * sizeof(float), stream);

  cvt_kernel<<<256, 256, 0, stream>>>(Wq, Wqb);
  cvt_kernel<<<256, 256, 0, stream>>>(Wk, Wkb);
  cvt_kernel<<<256, 256, 0, stream>>>(Wv, Wvb);
  cvt_kernel<<<256, 256, 0, stream>>>(Wo, Wob);

  ln_kernel<<<NTOK / 4, 256, 0, stream>>>(x, gamma, beta, xn);

  dim3 gg(NTOK / 128, Dc / 128);            // 64 x 4
  gemm_bf16<1><<<gg, 256, 0, stream>>>(xn, Wqb, nullptr, Qd, nullptr);
  gemm_bf16<1><<<gg, 256, 0, stream>>>(xn, Wkb, nullptr, Kd, nullptr);
  gemm_bf16<2><<<gg, 256, 0, stream>>>(xn, Wvb, nullptr, VT, vm);

  dim3 ga(Bc * Hc, Lc / 32);                // 32 x 64
  attn2<<<ga, 64, 0, stream>>>(Qd, Kd, VT, vm, tok, ao);

  gemm_bf16<0><<<gg, 256, 0, stream>>>(ao, Wob, x, out, nullptr);
}

// Round 6
// 123.492 us; speedup vs baseline: 22.6386x; 1.2915x over previous
//
#include <hip/hip_runtime.h>
#include <math.h>

typedef unsigned short u16;
typedef unsigned int u32;
typedef unsigned long long u64;
typedef float f32x4 __attribute__((ext_vector_type(4)));
typedef __bf16 bf16x8 __attribute__((ext_vector_type(8)));
typedef __bf16 bf16x4 __attribute__((ext_vector_type(4)));

constexpr int Bc = 4, Lc = 2048, Dc = 512, Hc = 8, DHc = 64;
constexpr int NTOK = Bc * Lc;          // 8192
constexpr float LN_EPS = 1e-5f;
constexpr int KS = 72;                 // gemm LDS row stride
constexpr int PS = 72;                 // attn P-scratch row stride
// fold 1/sqrt(Dh) * log2(e) into Q so softmax runs in exp2 domain
constexpr float QSCALE = 0.125f * 1.44269504088896340736f;

__device__ inline u16 bf_bits(float f) {
  return __builtin_bit_cast(u16, (__bf16)f);
}

// ---------------------------------------------------------------------------
// fp32 -> bf16 conversion of all 4 weight matrices in one dispatch
// ---------------------------------------------------------------------------
__global__ __launch_bounds__(256) void cvt4_kernel(const float* __restrict__ s0,
                                                   const float* __restrict__ s1,
                                                   const float* __restrict__ s2,
                                                   const float* __restrict__ s3,
                                                   u16* __restrict__ d0,
                                                   u16* __restrict__ d1,
                                                   u16* __restrict__ d2,
                                                   u16* __restrict__ d3) {
  int mat = blockIdx.x >> 8;
  int i = ((blockIdx.x & 255) * 256 + threadIdx.x) * 4;
  const float* s = (mat == 0) ? s0 : (mat == 1) ? s1 : (mat == 2) ? s2 : s3;
  u16* d = (mat == 0) ? d0 : (mat == 1) ? d1 : (mat == 2) ? d2 : d3;
  float4 v = *(const float4*)&s[i];
  bf16x4 o;
  o[0] = (__bf16)v.x; o[1] = (__bf16)v.y; o[2] = (__bf16)v.z; o[3] = (__bf16)v.w;
  *(bf16x4*)&d[i] = o;
}

// ---------------------------------------------------------------------------
// Pad-mask precompute: pm[b*32 + kt] = bitmask of (token == 0) for 64 keys
// ---------------------------------------------------------------------------
__global__ __launch_bounds__(256) void pmask_kernel(const int* __restrict__ tok,
                                                    u64* __restrict__ pm) {
  int wid = (blockIdx.x * 256 + threadIdx.x) >> 6;   // 0..127
  int lane = threadIdx.x & 63;
  u64 m = __ballot(tok[(size_t)wid * 64 + lane] == 0);
  if (lane == 0) pm[wid] = m;
}

// ---------------------------------------------------------------------------
// LayerNorm: one wave per row of 512, bf16 output
// ---------------------------------------------------------------------------
__global__ __launch_bounds__(256) void ln_kernel(const float* __restrict__ x,
                                                 const float* __restrict__ gamma,
                                                 const float* __restrict__ beta,
                                                 u16* __restrict__ xn) {
  int wave = threadIdx.x >> 6;
  int lane = threadIdx.x & 63;
  int row  = blockIdx.x * 4 + wave;
  const float* xr = x + (size_t)row * Dc;
  float4 v0 = ((const float4*)xr)[lane * 2];
  float4 v1 = ((const float4*)xr)[lane * 2 + 1];
  float sum = v0.x + v0.y + v0.z + v0.w + v1.x + v1.y + v1.z + v1.w;
  float sq  = v0.x*v0.x + v0.y*v0.y + v0.z*v0.z + v0.w*v0.w
            + v1.x*v1.x + v1.y*v1.y + v1.z*v1.z + v1.w*v1.w;
  #pragma unroll
  for (int off = 32; off > 0; off >>= 1) {
    sum += __shfl_xor(sum, off);
    sq  += __shfl_xor(sq, off);
  }
  float mu = sum * (1.0f / Dc);
  float rs = rsqrtf(sq * (1.0f / Dc) - mu * mu + LN_EPS);
  float4 g0 = ((const float4*)gamma)[lane * 2];
  float4 g1 = ((const float4*)gamma)[lane * 2 + 1];
  float4 b0 = ((const float4*)beta)[lane * 2];
  float4 b1 = ((const float4*)beta)[lane * 2 + 1];
  bf16x8 o;
  o[0] = (__bf16)((v0.x - mu) * rs * g0.x + b0.x);
  o[1] = (__bf16)((v0.y - mu) * rs * g0.y + b0.y);
  o[2] = (__bf16)((v0.z - mu) * rs * g0.z + b0.z);
  o[3] = (__bf16)((v0.w - mu) * rs * g0.w + b0.w);
  o[4] = (__bf16)((v1.x - mu) * rs * g1.x + b1.x);
  o[5] = (__bf16)((v1.y - mu) * rs * g1.y + b1.y);
  o[6] = (__bf16)((v1.z - mu) * rs * g1.z + b1.z);
  o[7] = (__bf16)((v1.w - mu) * rs * g1.w + b1.w);
  *(bf16x8*)&xn[(size_t)row * Dc + lane * 8] = o;
}

// ---------------------------------------------------------------------------
// bf16 MFMA GEMM: C[n][e] = sum_d A[n][d] * W[e][d]
// MODE 0: fp32 out [NTOK][Dc] + residual (out_f).
// MODE 3: fused QKV. W is [1536][512]; e<512 -> Q (scaled by QSCALE,
//         [B][H][L][DH]); e<1024 -> K (same layout); else V transposed
//         [B][H][DH][L] + atomic column-sum into vm.
// ---------------------------------------------------------------------------
template <int MODE>
__global__ __launch_bounds__(256) void gemm_bf16(const u16* __restrict__ A,
                                                 const u16* __restrict__ W,
                                                 const float* __restrict__ res,
                                                 float* __restrict__ out_f,
                                                 u16* __restrict__ o_q,
                                                 u16* __restrict__ o_k,
                                                 u16* __restrict__ o_v,
                                                 float* __restrict__ vm) {
  __shared__ u16 As[128 * KS];
  __shared__ u16 Bs[128 * KS];
  int tid = threadIdx.x;
  int lane = tid & 63;
  int w = tid >> 6;
  int wr = w >> 1, wc = w & 1;
  int cc = lane & 15, rb = lane >> 4;
  int n0 = blockIdx.x * 128;
  int e0 = blockIdx.y * 128;
  f32x4 acc[4][4] = {};
  for (int k0 = 0; k0 < Dc; k0 += 64) {
    #pragma unroll
    for (int u = 0; u < 4; u++) {
      int idx = u * 256 + tid;
      int row = idx >> 3;
      int col = (idx & 7) << 3;
      *(uint4*)&As[row * KS + col] = *(const uint4*)&A[(size_t)(n0 + row) * Dc + k0 + col];
      *(uint4*)&Bs[row * KS + col] = *(const uint4*)&W[(size_t)(e0 + row) * Dc + k0 + col];
    }
    __syncthreads();
    #pragma unroll
    for (int kk = 0; kk < 64; kk += 32) {
      bf16x8 aF[4], bF[4];
      #pragma unroll
      for (int m = 0; m < 4; m++)
        aF[m] = *(bf16x8*)&As[(wr * 64 + m * 16 + cc) * KS + kk + rb * 8];
      #pragma unroll
      for (int n = 0; n < 4; n++)
        bF[n] = *(bf16x8*)&Bs[(wc * 64 + n * 16 + cc) * KS + kk + rb * 8];
      #pragma unroll
      for (int m = 0; m < 4; m++)
        #pragma unroll
        for (int n = 0; n < 4; n++)
          acc[m][n] = __builtin_amdgcn_mfma_f32_16x16x32_bf16(aF[m], bF[n], acc[m][n], 0, 0, 0);
    }
    __syncthreads();
  }
  if (MODE == 3) {
    int bb = n0 >> 11;
    #pragma unroll
    for (int n = 0; n < 4; n++) {
      int c = e0 + wc * 64 + n * 16 + cc;          // 0..1535, frag-uniform matrix
      int mat = c >> 9;
      int cm = c & 511;
      int h = cm >> 6, dh = cm & 63;
      if (mat == 2) {
        // V transposed: [B][H][DH][L], l runs along j -> vector store
        float cp = 0.f;
        #pragma unroll
        for (int m = 0; m < 4; m++) {
          int l0 = (n0 + wr * 64 + m * 16 + rb * 4) & (Lc - 1);
          bf16x4 o4;
          o4[0] = (__bf16)acc[m][n][0]; o4[1] = (__bf16)acc[m][n][1];
          o4[2] = (__bf16)acc[m][n][2]; o4[3] = (__bf16)acc[m][n][3];
          *(bf16x4*)&o_v[((size_t)(bb * Hc + h) * DHc + dh) * Lc + l0] = o4;
          cp += (acc[m][n][0] + acc[m][n][1]) + (acc[m][n][2] + acc[m][n][3]);
        }
        cp += __shfl_xor(cp, 16);
        cp += __shfl_xor(cp, 32);
        if (lane < 16) atomicAdd(&vm[(bb * Hc + h) * DHc + dh], cp);
      } else {
        u16* dst = (mat == 0) ? o_q : o_k;
        float sc = (mat == 0) ? QSCALE : 1.0f;
        #pragma unroll
        for (int m = 0; m < 4; m++) {
          #pragma unroll
          for (int j = 0; j < 4; j++) {
            int r = n0 + wr * 64 + m * 16 + rb * 4 + j;
            int ll = r & (Lc - 1);
            dst[(((size_t)(bb * Hc + h)) * Lc + ll) * DHc + dh] = bf_bits(acc[m][n][j] * sc);
          }
        }
      }
    }
  } else {
    #pragma unroll
    for (int m = 0; m < 4; m++) {
      #pragma unroll
      for (int n = 0; n < 4; n++) {
        #pragma unroll
        for (int j = 0; j < 4; j++) {
          int r = n0 + wr * 64 + m * 16 + rb * 4 + j;
          int c = e0 + wc * 64 + n * 16 + cc;
          size_t o = (size_t)r * Dc + c;
          out_f[o] = acc[m][n][j] + res[o];
        }
      }
    }
  }
}

// ---------------------------------------------------------------------------
// Flash attention v3: 1 wave/block, QBLK=32, KVBLK=64, swapped QK^T,
// exp2-domain softmax (Q prescaled), scalar pad masks, in-wave pipelining:
// V loads at tile top, K(t+1) loaded right after QK^T, defer-max rescale.
// ---------------------------------------------------------------------------
__global__ __launch_bounds__(64) void attn3(const u16* __restrict__ Q,
                                            const u16* __restrict__ K,
                                            const u16* __restrict__ VT,
                                            const float* __restrict__ vm,
                                            const u64* __restrict__ pmask,
                                            u16* __restrict__ out) {
  __shared__ u16 Ps[32 * PS];
  int lane = threadIdx.x;
  int cc = lane & 15, rb = lane >> 4;
  int bh = blockIdx.x;
  int qt = (int)gridDim.y - 1 - (int)blockIdx.y;     // heavy q-tiles first
  int q0 = qt * 32;
  int b = bh >> 3, h = bh & 7;
  const u16* Qb = Q + (size_t)bh * Lc * DHc;
  const u16* Kb = K + (size_t)bh * Lc * DHc;
  const u16* Vb = VT + (size_t)bh * DHc * Lc;
  const u64* pmb = pmask + (b << 5);

  bf16x8 qF[2][2];
  #pragma unroll
  for (int qb = 0; qb < 2; qb++)
    #pragma unroll
    for (int kc = 0; kc < 2; kc++)
      qF[qb][kc] = *(const bf16x8*)&Qb[(size_t)(q0 + qb * 16 + cc) * DHc + kc * 32 + rb * 8];

  float mrow[2] = {-INFINITY, -INFINITY};
  float lrow[2] = {0.f, 0.f};
  f32x4 acc[2][4] = {};
  int nfull = q0 >> 6;

  // preload K tile 0
  bf16x8 kf[4][2];
  #pragma unroll
  for (int c = 0; c < 4; c++) {
    const u16* kp = &Kb[(size_t)(c * 16 + cc) * DHc + rb * 8];
    kf[c][0] = *(const bf16x8*)kp;
    kf[c][1] = *(const bf16x8*)(kp + 32);
  }

  for (int kt = 0; kt <= nfull; kt++) {
    int k0 = kt * 64;
    bool last = (kt == nfull);
    u64 pm = pmb[kt];                                // uniform scalar load
    // V loads for this tile — consumed ~PV, issue early
    bf16x8 vf[2][4];
    #pragma unroll
    for (int kc = 0; kc < 2; kc++)
      #pragma unroll
      for (int d0 = 0; d0 < 4; d0++)
        vf[kc][d0] = *(const bf16x8*)&Vb[(size_t)(d0 * 16 + cc) * Lc + k0 + kc * 32 + rb * 8];

    // S^T = K·Q^T (already in log2 domain; Q carries 0.125*log2e)
    f32x4 sq[2][4] = {};
    __builtin_amdgcn_s_setprio(1);
    #pragma unroll
    for (int c = 0; c < 4; c++) {
      #pragma unroll
      for (int qb = 0; qb < 2; qb++) {
        sq[qb][c] = __builtin_amdgcn_mfma_f32_16x16x32_bf16(kf[c][0], qF[qb][0], sq[qb][c], 0, 0, 0);
        sq[qb][c] = __builtin_amdgcn_mfma_f32_16x16x32_bf16(kf[c][1], qF[qb][1], sq[qb][c], 0, 0, 0);
      }
    }
    __builtin_amdgcn_s_setprio(0);
    // kf now dead — prefetch K for next tile (hides under softmax+PV)
    if (!last) {
      #pragma unroll
      for (int c = 0; c < 4; c++) {
        const u16* kp = &Kb[(size_t)(k0 + 64 + c * 16 + cc) * DHc + rb * 8];
        kf[c][0] = *(const bf16x8*)kp;
        kf[c][1] = *(const bf16x8*)(kp + 32);
      }
    }
    // pad mask (k = c*16 + rb*4 + j)
    #pragma unroll
    for (int c = 0; c < 4; c++) {
      u32 smr = (((u32)(pm >> (c * 16)) & 0xffffu) >> (rb * 4));
      #pragma unroll
      for (int qb = 0; qb < 2; qb++)
        #pragma unroll
        for (int j = 0; j < 4; j++)
          if ((smr >> j) & 1) sq[qb][c][j] = -INFINITY;
    }
    if (last) {                                      // causal only on boundary tile
      #pragma unroll
      for (int qb = 0; qb < 2; qb++) {
        int qrel = q0 + qb * 16 + cc - k0;
        #pragma unroll
        for (int c = 0; c < 4; c++)
          #pragma unroll
          for (int j = 0; j < 4; j++)
            if (c * 16 + rb * 4 + j > qrel) sq[qb][c][j] = -INFINITY;
      }
    }
    // online softmax, exp2 domain, defer-max (THR=8 -> P bounded by 2^8)
    #pragma unroll
    for (int qb = 0; qb < 2; qb++) {
      float m0 = fmaxf(fmaxf(sq[qb][0][0], sq[qb][0][1]), fmaxf(sq[qb][0][2], sq[qb][0][3]));
      float m1 = fmaxf(fmaxf(sq[qb][1][0], sq[qb][1][1]), fmaxf(sq[qb][1][2], sq[qb][1][3]));
      float m2 = fmaxf(fmaxf(sq[qb][2][0], sq[qb][2][1]), fmaxf(sq[qb][2][2], sq[qb][2][3]));
      float m3 = fmaxf(fmaxf(sq[qb][3][0], sq[qb][3][1]), fmaxf(sq[qb][3][2], sq[qb][3][3]));
      float mx = fmaxf(fmaxf(m0, m1), fmaxf(m2, m3));
      mx = fmaxf(mx, __shfl_xor(mx, 16));
      mx = fmaxf(mx, __shfl_xor(mx, 32));
      if (!__all(mx <= mrow[qb] + 8.f)) {            // grow max: rescale state
        float nm = fmaxf(mrow[qb], mx);
        float nm2 = fmaxf(nm, -1e30f);
        float alpha = exp2f(mrow[qb] - nm2);
        lrow[qb] *= alpha;
        #pragma unroll
        for (int d0 = 0; d0 < 4; d0++)
          #pragma unroll
          for (int j = 0; j < 4; j++)
            acc[qb][d0][j] *= alpha;
        mrow[qb] = nm;
      }
      float nm2 = fmaxf(mrow[qb], -1e30f);
      float rs = 0.f;
      #pragma unroll
      for (int c = 0; c < 4; c++) {
        f32x4 p;
        #pragma unroll
        for (int j = 0; j < 4; j++) p[j] = exp2f(sq[qb][c][j] - nm2);
        rs += (p[0] + p[1]) + (p[2] + p[3]);
        bf16x4 p4;
        p4[0] = (__bf16)p[0]; p4[1] = (__bf16)p[1];
        p4[2] = (__bf16)p[2]; p4[3] = (__bf16)p[3];
        *(bf16x4*)&Ps[(qb * 16 + cc) * PS + c * 16 + rb * 4] = p4;
      }
      rs += __shfl_xor(rs, 16);
      rs += __shfl_xor(rs, 32);
      lrow[qb] += rs;
    }
    asm volatile("s_waitcnt lgkmcnt(0)" ::: "memory");   // wave-local RAW on Ps
    __builtin_amdgcn_sched_barrier(0);                   // rule #18
    // O^T += V^T · P^T
    __builtin_amdgcn_s_setprio(1);
    #pragma unroll
    for (int kc = 0; kc < 2; kc++) {
      bf16x8 pF0 = *(bf16x8*)&Ps[(size_t)cc * PS + kc * 32 + rb * 8];
      bf16x8 pF1 = *(bf16x8*)&Ps[(size_t)(16 + cc) * PS + kc * 32 + rb * 8];
      #pragma unroll
      for (int d0 = 0; d0 < 4; d0++) {
        acc[0][d0] = __builtin_amdgcn_mfma_f32_16x16x32_bf16(vf[kc][d0], pF0, acc[0][d0], 0, 0, 0);
        acc[1][d0] = __builtin_amdgcn_mfma_f32_16x16x32_bf16(vf[kc][d0], pF1, acc[1][d0], 0, 0, 0);
      }
    }
    __builtin_amdgcn_s_setprio(0);
  }
  // epilogue: normalize; all-masked rows -> uniform mean of ALL V rows
  #pragma unroll
  for (int qb = 0; qb < 2; qb++) {
    int q = q0 + qb * 16 + cc;
    bool ok = lrow[qb] > 0.f;
    float inv = ok ? 1.0f / lrow[qb] : 0.f;
    #pragma unroll
    for (int d0 = 0; d0 < 4; d0++) {
      bf16x4 o4;
      #pragma unroll
      for (int j = 0; j < 4; j++) {
        float v = ok ? acc[qb][d0][j] * inv
                     : vm[bh * DHc + d0 * 16 + rb * 4 + j] * (1.0f / Lc);
        o4[j] = (__bf16)v;
      }
      *(bf16x4*)&out[((size_t)(b * Lc + q)) * Dc + h * DHc + d0 * 16 + rb * 4] = o4;
    }
  }
}

// ---------------------------------------------------------------------------
// Launch
// ---------------------------------------------------------------------------
extern "C" void kernel_launch(void* const* d_in, const int* in_sizes, int n_in,
                              void* d_out, int out_size, void* d_ws, size_t ws_size,
                              hipStream_t stream) {
  const float* x     = (const float*)d_in[0];
  const int*   tok   = (const int*)d_in[1];
  const float* Wq    = (const float*)d_in[2];
  const float* Wk    = (const float*)d_in[3];
  const float* Wv    = (const float*)d_in[4];
  const float* Wo    = (const float*)d_in[5];
  const float* gamma = (const float*)d_in[6];
  const float* beta  = (const float*)d_in[7];
  float* out = (float*)d_out;

  const size_t SEG = (size_t)NTOK * Dc;     // 4,194,304 elems
  const size_t WSEG = (size_t)Dc * Dc;      // 262,144 elems
  u16* xn   = (u16*)d_ws;
  u16* Qd   = xn + SEG;
  u16* Kd   = Qd + SEG;
  u16* VT   = Kd + SEG;
  u16* ao   = VT + SEG;
  u16* Wqkv = ao + SEG;                     // 3*WSEG (Q,K,V rows stacked)
  u16* Wob  = Wqkv + 3 * WSEG;
  float* vm = (float*)(Wob + WSEG);         // 2048 f32
  u64* pmarr = (u64*)(vm + (size_t)Bc * Hc * DHc);  // 128 u64

  (void)hipMemsetAsync(vm, 0, (size_t)Bc * Hc * DHc * sizeof(float), stream);

  cvt4_kernel<<<1024, 256, 0, stream>>>(Wq, Wk, Wv, Wo,
                                        Wqkv, Wqkv + WSEG, Wqkv + 2 * WSEG, Wob);
  ln_kernel<<<NTOK / 4, 256, 0, stream>>>(x, gamma, beta, xn);
  pmask_kernel<<<32, 256, 0, stream>>>(tok, pmarr);

  dim3 gq(NTOK / 128, (3 * Dc) / 128);      // 64 x 12
  gemm_bf16<3><<<gq, 256, 0, stream>>>(xn, Wqkv, nullptr, nullptr, Qd, Kd, VT, vm);

  dim3 ga(Bc * Hc, Lc / 32);                // 32 x 64
  attn3<<<ga, 64, 0, stream>>>(Qd, Kd, VT, vm, pmarr, ao);

  dim3 gg(NTOK / 128, Dc / 128);            // 64 x 4
  gemm_bf16<0><<<gg, 256, 0, stream>>>(ao, Wob, x, out, nullptr, nullptr, nullptr, nullptr);
}